// Round 7
// baseline (534.723 us; speedup 1.0000x reference)
//
#include <hip/hip_runtime.h>
#include <hip/hip_cooperative_groups.h>
#include <cstdint>

namespace cg = cooperative_groups;

typedef unsigned short u16;
typedef __bf16 bf16x8 __attribute__((ext_vector_type(8)));
typedef float floatx4 __attribute__((ext_vector_type(4)));

// ---------------- constants ----------------
#define BB 16
#define PP 2048
#define EE 768
#define HH 256
#define PE (PP * EE)          // 1572864
#define MM (BB * PP)          // 32768

__device__ __forceinline__ u16 f2bf(float f) {
  union { float f; uint32_t u; } v; v.f = f;
  return (u16)((v.u + 0x7fffu + ((v.u >> 16) & 1u)) >> 16);
}

__device__ __forceinline__ void gload16(const void* g, void* l) {
  typedef __attribute__((address_space(1))) const void GV;
  typedef __attribute__((address_space(3))) void LV;
  __builtin_amdgcn_global_load_lds((GV*)g, (LV*)l, 16, 0, 0);
}

// bijective XCD swizzle (nwg % 8 == 0): XCD c handles contiguous logical chunk
__device__ __forceinline__ int xcd_remap(int orig, int nwg) {
  return (orig & 7) * (nwg >> 3) + (orig >> 3);
}

// ---- 128x128-tile TN GEMM core: A[M][K] rowmajor(lda), B[N][K] rowmajor(ldb),
// BK=64, 256 threads = 4 waves (2x2), each wave 64x64 = 4x4 frags of 16x16x32.
__device__ __forceinline__ void zero_acc4(floatx4 acc[4][4]) {
  const floatx4 z = {0.f, 0.f, 0.f, 0.f};
#pragma unroll
  for (int i = 0; i < 4; ++i)
#pragma unroll
    for (int j = 0; j < 4; ++j) acc[i][j] = z;
}

__device__ __forceinline__ void gemm_core(const u16* A, int lda, const u16* B, int ldb,
                                          int kIters, u16* As, u16* Bs,
                                          floatx4 acc[4][4]) {
  const int tid  = threadIdx.x;
  const int lane = tid & 63;
  const int wr   = (tid >> 7) & 1;
  const int wc   = (tid >> 6) & 1;
  const int srow = tid >> 3;           // 0..31
  const int scol = (tid & 7) << 3;     // 0..56
  const int mrow = lane & 15;
  const int kgrp = (lane >> 4) << 3;   // 0,8,16,24
  for (int kk = 0; kk < kIters; ++kk) {
    const u16* Ak = A + kk * 64;
    const u16* Bk = B + kk * 64;
    __syncthreads();  // previous compute/epilogue reads done before LDS overwrite
#pragma unroll
    for (int r = 0; r < 4; ++r) {
      gload16(Ak + (size_t)(r * 32 + srow) * lda + scol, (char*)As + r * 4096 + tid * 16);
      gload16(Bk + (size_t)(r * 32 + srow) * ldb + scol, (char*)Bs + r * 4096 + tid * 16);
    }
    __syncthreads();  // compiler drains vmcnt before barrier
#pragma unroll
    for (int kp = 0; kp < 2; ++kp) {
      const int ko = kp * 32 + kgrp;
      bf16x8 af[4], bq[4];
#pragma unroll
      for (int i = 0; i < 4; ++i) {
        af[i] = *(const bf16x8*)(As + (wr * 64 + i * 16 + mrow) * 64 + ko);
        bq[i] = *(const bf16x8*)(Bs + (wc * 64 + i * 16 + mrow) * 64 + ko);
      }
#pragma unroll
      for (int i = 0; i < 4; ++i)
#pragma unroll
        for (int j = 0; j < 4; ++j)
          acc[i][j] = __builtin_amdgcn_mfma_f32_16x16x32_bf16(af[i], bq[j], acc[i][j], 0, 0, 0);
    }
  }
}

template <typename F>
__device__ __forceinline__ void epilogue4(floatx4 acc[4][4], F f) {
  const int lane = threadIdx.x & 63;
  const int wr = (threadIdx.x >> 7) & 1, wc = (threadIdx.x >> 6) & 1;
  const int r0 = (lane >> 4) * 4, c0 = lane & 15;
#pragma unroll
  for (int i = 0; i < 4; ++i)
#pragma unroll
    for (int j = 0; j < 4; ++j)
#pragma unroll
      for (int r = 0; r < 4; ++r)
        f(wr * 64 + i * 16 + r0 + r, wc * 64 + j * 16 + c0, acc[i][j][r]);
}

// ================= phase bodies (verbatim round-4 kernels) =================

// QKV GEMM + fused K/V transpose. t is the REMAPPED tile index in [0,1536).
__device__ __forceinline__ void phase_qkv(int t, const u16* __restrict__ xn,
                                          const u16* __restrict__ wT,
                                          u16* __restrict__ q_buf,
                                          u16* __restrict__ kT,
                                          u16* __restrict__ vT,
                                          u16* As, u16* Bs) {
  floatx4 acc[4][4];
  zero_acc4(acc);
  const int xt = t % 6, yt = t / 6;          // yt in [0,256): b = yt>>4, ptile = yt&15
  const int tM = yt * 128, tN = xt * 128;
  gemm_core(xn + (size_t)tM * EE, EE, wT + (size_t)tN * EE, EE, 12, As, Bs, acc);

  if (xt < 2) {
    epilogue4(acc, [&](int gr, int gc, float v) {
      q_buf[(size_t)(tM + gr) * HH + xt * 128 + gc] = f2bf(v);
    });
  } else {
    const int b = yt >> 4;
    const int p_base = (yt & 15) * 128;      // p index local to batch
    u16* dst = ((xt < 4) ? kT : vT) + (size_t)b * (HH * PP);
    const int dbase = (xt - ((xt < 4) ? 2 : 4)) * 128;
    u16 (*tp)[144] = (u16(*)[144])As;        // 64 x 144 (18432 B <= 32768)
    const int tid = threadIdx.x;
    const int lane = tid & 63;
    const int wr = (tid >> 7) & 1, wc = (tid >> 6) & 1;
    const int r0 = (lane >> 4) * 4, c0 = lane & 15;
#pragma unroll
    for (int h = 0; h < 2; ++h) {
      __syncthreads();  // LDS free (gemm reads done / prior readout done)
      if (wc == h) {
#pragma unroll
        for (int i = 0; i < 4; ++i)
#pragma unroll
          for (int j = 0; j < 4; ++j)
#pragma unroll
            for (int r = 0; r < 4; ++r)
              tp[j * 16 + c0][wr * 64 + i * 16 + r0 + r] = f2bf(acc[i][j][r]);
      }
      __syncthreads();
#pragma unroll
      for (int pass = 0; pass < 4; ++pass) {
        const int row = pass * 16 + (tid >> 4);   // 0..63 (local d within half)
        const int p8 = (tid & 15) * 8;            // 0..120 (local p, x8 u16)
        const int d = dbase + h * 64 + row;
        uint4 vdat = *(const uint4*)&tp[row][p8];
        *(uint4*)&dst[(size_t)d * PP + p_base + p8] = vdat;
      }
    }
  }
}

// G[d1][d2] split-K partials. t in [0,512).
__device__ __forceinline__ void phase_w2(int t, const u16* __restrict__ kT,
                                         const u16* __restrict__ vT,
                                         float* __restrict__ part,
                                         u16* As, u16* Bs) {
  floatx4 acc[4][4];
  zero_acc4(acc);
  const int xt = t & 1, yt = (t >> 1) & 1, z = t >> 2;  // z = b*8+s
  const int b = z >> 3, s = z & 7;
  const int tM = yt * 128, tN = xt * 128;
  const u16* A = kT + (size_t)b * (HH * PP) + (size_t)tM * PP + s * 256;
  const u16* B = vT + (size_t)b * (HH * PP) + (size_t)tN * PP + s * 256;
  gemm_core(A, PP, B, PP, 4, As, Bs, acc);
  float* P = part + (size_t)z * 65536;
  epilogue4(acc, [&](int gr, int gc, float v) {
    P[(size_t)(tM + gr) * 256 + tN + gc] = v;
  });
}

// reduce 8 partials -> W2 bf16. idx in [0, 16*65536).
__device__ __forceinline__ void phase_rw2(int idx, const float* __restrict__ part,
                                          u16* __restrict__ W2) {
  const int b = idx >> 16, i = idx & 65535;
  const float* p = part + ((size_t)b << 19) + i;
  float s = 0.f;
#pragma unroll
  for (int t = 0; t < 8; ++t) s += p[(size_t)t << 16];
  W2[idx] = f2bf(s);
}

// M2T[e][d1] = sum_d2 lw[e][d2] * G[d1][d2]. t in [0,192).
__device__ __forceinline__ void phase_m2(int t, const u16* __restrict__ lwB,
                                         const u16* __restrict__ W2,
                                         u16* __restrict__ M2T,
                                         u16* As, u16* Bs) {
  floatx4 acc[4][4];
  zero_acc4(acc);
  const int xt = t & 1, yt = (t >> 1) % 6, b = t / 12;
  const int tM = yt * 128, tN = xt * 128;
  const u16* A = lwB + (size_t)tM * HH;
  const u16* B = W2 + (size_t)b * 65536 + (size_t)tN * HH;
  gemm_core(A, HH, B, HH, 4, As, Bs, acc);
  u16* Mb = M2T + (size_t)b * (EE * HH);
  epilogue4(acc, [&](int gr, int gc, float v) {
    Mb[(size_t)(tM + gr) * HH + tN + gc] = f2bf(v);
  });
}

// out[p][e] = relu(q @ M2T^T + lb). t in [0,1536).
__device__ __forceinline__ void phase_out(int t, const u16* __restrict__ q_buf,
                                          const u16* __restrict__ M2T,
                                          const float* __restrict__ lb,
                                          float* __restrict__ out,
                                          u16* As, u16* Bs) {
  floatx4 acc[4][4];
  zero_acc4(acc);
  const int xt = t % 6, yt = (t / 6) % 16, b = t / 96;
  const int tM = yt * 128, tN = xt * 128;
  const u16* A = q_buf + (size_t)b * (PP * HH) + (size_t)tM * HH;
  const u16* B = M2T + (size_t)b * (EE * HH) + (size_t)tN * HH;
  gemm_core(A, HH, B, HH, 4, As, Bs, acc);
  float* ob = out + (size_t)b * PE;
  epilogue4(acc, [&](int gr, int gc, float v) {
    ob[(size_t)(tM + gr) * EE + tN + gc] = fmaxf(v + lb[tN + gc], 0.f);
  });
}

// ================= cooperative mega-kernel =================
__global__ __launch_bounds__(256, 2) void k_coop(const u16* __restrict__ xn,
                                                 const u16* __restrict__ qwT,
                                                 u16* __restrict__ q_buf,
                                                 u16* __restrict__ kT,
                                                 u16* __restrict__ vT,
                                                 float* __restrict__ part,
                                                 u16* __restrict__ W2,
                                                 const u16* __restrict__ lwB,
                                                 u16* __restrict__ M2T,
                                                 const float* __restrict__ lb,
                                                 float* __restrict__ out) {
  __shared__ __align__(16) u16 sbuf[128 * 64 * 2];
  u16* As = sbuf;
  u16* Bs = sbuf + 128 * 64;
  cg::grid_group g = cg::this_grid();
  const int nb = gridDim.x, bid = blockIdx.x;

  for (int tt = bid; tt < 1536; tt += nb)
    phase_qkv(xcd_remap(tt, 1536), xn, qwT, q_buf, kT, vT, As, Bs);
  g.sync();
  for (int tt = bid; tt < 512; tt += nb)
    phase_w2(xcd_remap(tt, 512), kT, vT, part, As, Bs);
  g.sync();
  for (int idx = bid * 256 + (int)threadIdx.x; idx < (BB << 16); idx += nb * 256)
    phase_rw2(idx, part, W2);
  g.sync();
  for (int tt = bid; tt < 192; tt += nb)
    phase_m2(xcd_remap(tt, 192), lwB, W2, M2T, As, Bs);
  g.sync();
  for (int tt = bid; tt < 1536; tt += nb)
    phase_out(xcd_remap(tt, 1536), q_buf, M2T, lb, out, As, Bs);
}

// ================= fallback separate kernels (round-4 structure) =================
__global__ __launch_bounds__(256) void k_gemm_qkv(const u16* __restrict__ xn,
                                                  const u16* __restrict__ wT,
                                                  u16* __restrict__ q_buf,
                                                  u16* __restrict__ kT,
                                                  u16* __restrict__ vT) {
  __shared__ __align__(16) u16 sbuf[128 * 64 * 2];
  phase_qkv(xcd_remap(blockIdx.x, 1536), xn, wT, q_buf, kT, vT, sbuf, sbuf + 128 * 64);
}

__global__ __launch_bounds__(256) void k_gemm_w2(const u16* __restrict__ kT,
                                                 const u16* __restrict__ vT,
                                                 float* __restrict__ part) {
  __shared__ __align__(16) u16 sbuf[128 * 64 * 2];
  phase_w2(xcd_remap(blockIdx.x, 512), kT, vT, part, sbuf, sbuf + 128 * 64);
}

__global__ void k_reduce_w2(const float* __restrict__ part, u16* __restrict__ W2) {
  phase_rw2(blockIdx.x * 256 + threadIdx.x, part, W2);
}

__global__ __launch_bounds__(256) void k_gemm_m2(const u16* __restrict__ lwB,
                                                 const u16* __restrict__ W2,
                                                 u16* __restrict__ M2T) {
  __shared__ __align__(16) u16 sbuf[128 * 64 * 2];
  phase_m2(xcd_remap(blockIdx.x, 192), lwB, W2, M2T, sbuf, sbuf + 128 * 64);
}

__global__ __launch_bounds__(256) void k_gemm_out(const u16* __restrict__ q_buf,
                                                  const u16* __restrict__ M2T,
                                                  const float* __restrict__ lb,
                                                  float* __restrict__ out) {
  __shared__ __align__(16) u16 sbuf[128 * 64 * 2];
  phase_out(xcd_remap(blockIdx.x, 1536), q_buf, M2T, lb, out, sbuf, sbuf + 128 * 64);
}

// ---------------- LayerNorm ----------------
__global__ __launch_bounds__(256) void k_reduce1(const float* __restrict__ x,
                                                 float* __restrict__ psum,
                                                 float* __restrict__ psq) {
  const int b = blockIdx.y, blk = blockIdx.x, tid = threadIdx.x;
  const float4* xb = (const float4*)(x + (size_t)b * PE + (size_t)blk * 12288);
  float s = 0.f, q = 0.f;
#pragma unroll
  for (int i = 0; i < 12; ++i) {
    float4 v = xb[tid + i * 256];
    s += v.x + v.y + v.z + v.w;
    q += v.x * v.x + v.y * v.y + v.z * v.z + v.w * v.w;
  }
  for (int off = 32; off > 0; off >>= 1) { s += __shfl_down(s, off); q += __shfl_down(q, off); }
  __shared__ float ls[4], lq[4];
  if ((tid & 63) == 0) { ls[tid >> 6] = s; lq[tid >> 6] = q; }
  __syncthreads();
  if (tid == 0) {
    psum[b * 128 + blk] = ls[0] + ls[1] + ls[2] + ls[3];
    psq [b * 128 + blk] = lq[0] + lq[1] + lq[2] + lq[3];
  }
}

__global__ void k_reduce2(const float* __restrict__ psum, const float* __restrict__ psq,
                          float* __restrict__ stats) {
  const int b = blockIdx.x, tid = threadIdx.x;  // 128 threads
  float s = psum[b * 128 + tid], q = psq[b * 128 + tid];
  for (int off = 32; off > 0; off >>= 1) { s += __shfl_down(s, off); q += __shfl_down(q, off); }
  __shared__ float ls[2], lq[2];
  if ((tid & 63) == 0) { ls[tid >> 6] = s; lq[tid >> 6] = q; }
  __syncthreads();
  if (tid == 0) {
    float S = ls[0] + ls[1], Q = lq[0] + lq[1];
    const float invN = 1.f / (float)PE;
    float mean = S * invN;
    float var = Q * invN - mean * mean;
    stats[b * 2] = mean;
    stats[b * 2 + 1] = rsqrtf(var + 1e-5f);
  }
}

__global__ __launch_bounds__(256) void k_ln(const float* __restrict__ x,
                                            const float* __restrict__ w,
                                            const float* __restrict__ bia,
                                            const float* __restrict__ stats,
                                            u16* __restrict__ xn) {
  const float4* x4 = (const float4*)x;
  const float4* w4 = (const float4*)w;
  const float4* b4 = (const float4*)bia;
  for (int vi = blockIdx.x * 256 + threadIdx.x; vi < (PE / 4) * BB; vi += gridDim.x * 256) {
    int bidx = vi / (PE / 4);
    int wi = vi - bidx * (PE / 4);
    float4 xv = x4[vi], wv = w4[wi], bv = b4[wi];
    float mean = stats[bidx * 2], rstd = stats[bidx * 2 + 1];
    ushort4 o;
    o.x = f2bf((xv.x - mean) * rstd * wv.x + bv.x);
    o.y = f2bf((xv.y - mean) * rstd * wv.y + bv.y);
    o.z = f2bf((xv.z - mean) * rstd * wv.z + bv.z);
    o.w = f2bf((xv.w - mean) * rstd * wv.w + bv.w);
    ((ushort4*)xn)[vi] = o;
  }
}

// ---------------- weight prep (merged transpose_w + cast) ----------------
__global__ __launch_bounds__(256) void k_prep(const float* __restrict__ qw,
                                              u16* __restrict__ qwT,
                                              const float* __restrict__ lw,
                                              u16* __restrict__ lwB) {
  if (blockIdx.x < 576) {
    // qkv_w [E][3H] fp32 -> qwT [n][e] bf16 (32x32 tile transpose)
    __shared__ float tsh[32][33];
    const int bx = blockIdx.x % 24, by = blockIdx.x / 24;
    const int e0 = bx * 32, n0 = by * 32;
    const int tx = threadIdx.x & 31, ty = threadIdx.x >> 5;  // 32x8
#pragma unroll
    for (int j = 0; j < 4; ++j)
      tsh[ty + j * 8][tx] = qw[(size_t)(e0 + ty + j * 8) * 768 + n0 + tx];
    __syncthreads();
#pragma unroll
    for (int j = 0; j < 4; ++j)
      qwT[(size_t)(n0 + ty + j * 8) * 768 + e0 + tx] = f2bf(tsh[tx][ty + j * 8]);
  } else {
    // lin_w fp32 -> bf16 (rowmajor [E][H], already k-contiguous)
    const int i = (blockIdx.x - 576) * 256 + threadIdx.x;
    if (i < 768 * 256 / 4) {
      float4 v = ((const float4*)lw)[i];
      ushort4 o;
      o.x = f2bf(v.x); o.y = f2bf(v.y); o.z = f2bf(v.z); o.w = f2bf(v.w);
      ((ushort4*)lwB)[i] = o;
    }
  }
}

// ---------------- launch ----------------
extern "C" void kernel_launch(void* const* d_in, const int* in_sizes, int n_in,
                              void* d_out, int out_size, void* d_ws, size_t ws_size,
                              hipStream_t stream) {
  (void)in_sizes; (void)n_in; (void)out_size;
  const float* x  = (const float*)d_in[0];
  const float* nw = (const float*)d_in[1];
  const float* nb = (const float*)d_in[2];
  const float* qw = (const float*)d_in[3];
  const float* lw = (const float*)d_in[4];
  const float* lb = (const float*)d_in[5];
  float* out = (float*)d_out;
  char* ws = (char*)d_ws;

  size_t off = 0;
  auto alloc = [&](size_t bytes) { size_t o = off; off += (bytes + 255) & ~(size_t)255; return o; };
  const size_t o_psum = alloc(16 * 128 * 4);
  const size_t o_psq  = alloc(16 * 128 * 4);
  const size_t o_st   = alloc(16 * 2 * 4);
  const size_t o_qwT  = alloc((size_t)768 * 768 * 2);
  const size_t o_lwB  = alloc((size_t)768 * 256 * 2);
  const size_t o_q    = alloc((size_t)MM * HH * 2);        // 16.8 MB
  const size_t o_kT   = alloc((size_t)BB * HH * PP * 2);   // 16.8 MB
  const size_t o_vT   = alloc((size_t)BB * HH * PP * 2);   // 16.8 MB
  const size_t o_W2   = alloc((size_t)BB * HH * HH * 2);   // 2.1 MB
  const size_t o_M2T  = alloc((size_t)BB * EE * HH * 2);   // 6.3 MB
  const size_t need_base = off;
  const size_t region = (size_t)MM * EE * 2;  // xn (50.3MB) >= part (33.6MB)

  // xn and part have disjoint lifetimes -> share one region; spill to d_out
  // (100.7MB fp32, dead until the final phase) if ws is too small.
  char* big = (ws_size >= need_base + region) ? (ws + need_base) : (char*)d_out;

  float* psum = (float*)(ws + o_psum);
  float* psq  = (float*)(ws + o_psq);
  float* st   = (float*)(ws + o_st);
  u16* qwT    = (u16*)(ws + o_qwT);
  u16* lwB    = (u16*)(ws + o_lwB);
  u16* q_buf  = (u16*)(ws + o_q);
  u16* kT     = (u16*)(ws + o_kT);
  u16* vT     = (u16*)(ws + o_vT);
  u16* W2     = (u16*)(ws + o_W2);
  u16* M2T    = (u16*)(ws + o_M2T);
  const u16* xn = (const u16*)big;
  u16* xn_w   = (u16*)big;
  float* part = (float*)big;

  // LN + weight prep
  k_reduce1<<<dim3(128, 16), 256, 0, stream>>>(x, psum, psq);
  k_reduce2<<<16, 128, 0, stream>>>(psum, psq, st);
  k_ln<<<2048, 256, 0, stream>>>(x, nw, nb, st, xn_w);
  k_prep<<<768, 256, 0, stream>>>(qw, qwT, lw, lwB);

  // cooperative fused pipeline: qkv -> w2 -> reduce -> m2 -> out
  int dev = 0;
  hipGetDevice(&dev);
  int coop = 0;
  hipDeviceGetAttribute(&coop, hipDeviceAttributeCooperativeLaunch, dev);
  int maxb = 0;
  hipOccupancyMaxActiveBlocksPerMultiprocessor(&maxb, k_coop, 256, 0);
  int grid = maxb * 256;
  if (grid > 1536) grid = 1536;

  bool done = false;
  if (coop && grid >= 256) {
    void* args[] = {(void*)&xn, (void*)&qwT, (void*)&q_buf, (void*)&kT, (void*)&vT,
                    (void*)&part, (void*)&W2, (void*)&lwB, (void*)&M2T, (void*)&lb,
                    (void*)&out};
    hipError_t e = hipLaunchCooperativeKernel(k_coop, dim3(grid), dim3(256), args, 0, stream);
    done = (e == hipSuccess);
  }
  if (!done) {
    k_gemm_qkv<<<1536, 256, 0, stream>>>(xn, qwT, q_buf, kT, vT);
    k_gemm_w2<<<512, 256, 0, stream>>>(kT, vT, part);
    k_reduce_w2<<<4096, 256, 0, stream>>>(part, W2);
    k_gemm_m2<<<192, 256, 0, stream>>>(lwB, W2, M2T);
    k_gemm_out<<<1536, 256, 0, stream>>>(q_buf, M2T, lb, out);
  }
}

// Round 8
// 351.453 us; speedup vs baseline: 1.5215x; 1.5215x over previous
//
#include <hip/hip_runtime.h>
#include <cstdint>

typedef unsigned short u16;
typedef __bf16 bf16x8 __attribute__((ext_vector_type(8)));
typedef float floatx4 __attribute__((ext_vector_type(4)));

// ---------------- constants ----------------
#define BB 16
#define PP 2048
#define EE 768
#define HH 256
#define PE (PP * EE)          // 1572864
#define MM (BB * PP)          // 32768

__device__ __forceinline__ u16 f2bf(float f) {
  union { float f; uint32_t u; } v; v.f = f;
  return (u16)((v.u + 0x7fffu + ((v.u >> 16) & 1u)) >> 16);
}

__device__ __forceinline__ void gload16(const void* g, void* l) {
  typedef __attribute__((address_space(1))) const void GV;
  typedef __attribute__((address_space(3))) void LV;
  __builtin_amdgcn_global_load_lds((GV*)g, (LV*)l, 16, 0, 0);
}

// bijective XCD swizzle (nwg % 8 == 0)
__device__ __forceinline__ int xcd_remap(int orig, int nwg) {
  return (orig & 7) * (nwg >> 3) + (orig >> 3);
}

// ======== 128x128 4-wave TN core (proven; used by qkv only) ========
__device__ __forceinline__ void zero_acc4(floatx4 acc[4][4]) {
  const floatx4 z = {0.f, 0.f, 0.f, 0.f};
#pragma unroll
  for (int i = 0; i < 4; ++i)
#pragma unroll
    for (int j = 0; j < 4; ++j) acc[i][j] = z;
}

__device__ __forceinline__ void gemm_core(const u16* A, int lda, const u16* B, int ldb,
                                          int kIters, u16* As, u16* Bs,
                                          floatx4 acc[4][4]) {
  const int tid  = threadIdx.x;
  const int lane = tid & 63;
  const int wr   = (tid >> 7) & 1;
  const int wc   = (tid >> 6) & 1;
  const int srow = tid >> 3;           // 0..31
  const int scol = (tid & 7) << 3;     // 0..56
  const int mrow = lane & 15;
  const int kgrp = (lane >> 4) << 3;   // 0,8,16,24
  for (int kk = 0; kk < kIters; ++kk) {
    const u16* Ak = A + kk * 64;
    const u16* Bk = B + kk * 64;
    __syncthreads();
#pragma unroll
    for (int r = 0; r < 4; ++r) {
      gload16(Ak + (size_t)(r * 32 + srow) * lda + scol, (char*)As + r * 4096 + tid * 16);
      gload16(Bk + (size_t)(r * 32 + srow) * ldb + scol, (char*)Bs + r * 4096 + tid * 16);
    }
    __syncthreads();
#pragma unroll
    for (int kp = 0; kp < 2; ++kp) {
      const int ko = kp * 32 + kgrp;
      bf16x8 af[4], bq[4];
#pragma unroll
      for (int i = 0; i < 4; ++i) {
        af[i] = *(const bf16x8*)(As + (wr * 64 + i * 16 + mrow) * 64 + ko);
        bq[i] = *(const bf16x8*)(Bs + (wc * 64 + i * 16 + mrow) * 64 + ko);
      }
#pragma unroll
      for (int i = 0; i < 4; ++i)
#pragma unroll
        for (int j = 0; j < 4; ++j)
          acc[i][j] = __builtin_amdgcn_mfma_f32_16x16x32_bf16(af[i], bq[j], acc[i][j], 0, 0, 0);
    }
  }
}

// ======== 64x64 1-wave TN core (barrier-free; for short-K tail GEMMs) ========
// 64 thr = 1 wave; LDS 2x8KB; __syncthreads on 1 wave = waitcnt only (no
// cross-wave barrier stall). acc[4][4] covers the full 64x64 tile.
__device__ __forceinline__ void gemm64_core(const u16* A, int lda, const u16* B, int ldb,
                                            int kIters, u16* As, u16* Bs,
                                            floatx4 acc[4][4]) {
  const int tid  = threadIdx.x;        // 0..63
  const int srow = tid >> 3;           // 0..7
  const int scol = (tid & 7) << 3;     // 0..56
  const int mrow = tid & 15;
  const int kgrp = (tid >> 4) << 3;    // 0,8,16,24
  for (int kk = 0; kk < kIters; ++kk) {
    const u16* Ak = A + kk * 64;
    const u16* Bk = B + kk * 64;
    __syncthreads();                   // lgkm drain: prior ds_reads done
#pragma unroll
    for (int r = 0; r < 8; ++r) {
      gload16(Ak + (size_t)(r * 8 + srow) * lda + scol, (char*)As + r * 1024 + tid * 16);
      gload16(Bk + (size_t)(r * 8 + srow) * ldb + scol, (char*)Bs + r * 1024 + tid * 16);
    }
    __syncthreads();                   // vm drain: staged data landed
#pragma unroll
    for (int kp = 0; kp < 2; ++kp) {
      const int ko = kp * 32 + kgrp;
      bf16x8 af[4], bq[4];
#pragma unroll
      for (int i = 0; i < 4; ++i) {
        af[i] = *(const bf16x8*)(As + (i * 16 + mrow) * 64 + ko);
        bq[i] = *(const bf16x8*)(Bs + (i * 16 + mrow) * 64 + ko);
      }
#pragma unroll
      for (int i = 0; i < 4; ++i)
#pragma unroll
        for (int j = 0; j < 4; ++j)
          acc[i][j] = __builtin_amdgcn_mfma_f32_16x16x32_bf16(af[i], bq[j], acc[i][j], 0, 0, 0);
    }
  }
}

template <typename F>
__device__ __forceinline__ void epilogue64(floatx4 acc[4][4], F f) {
  const int lane = threadIdx.x & 63;
  const int r0 = (lane >> 4) * 4, c0 = lane & 15;
#pragma unroll
  for (int i = 0; i < 4; ++i)
#pragma unroll
    for (int j = 0; j < 4; ++j)
#pragma unroll
      for (int r = 0; r < 4; ++r)
        f(i * 16 + r0 + r, j * 16 + c0, acc[i][j][r]);
}

template <typename F>
__device__ __forceinline__ void epilogue4(floatx4 acc[4][4], F f) {
  const int lane = threadIdx.x & 63;
  const int wr = (threadIdx.x >> 7) & 1, wc = (threadIdx.x >> 6) & 1;
  const int r0 = (lane >> 4) * 4, c0 = lane & 15;
#pragma unroll
  for (int i = 0; i < 4; ++i)
#pragma unroll
    for (int j = 0; j < 4; ++j)
#pragma unroll
      for (int r = 0; r < 4; ++r)
        f(wr * 64 + i * 16 + r0 + r, wc * 64 + j * 16 + c0, acc[i][j][r]);
}

// ---------------- LN stats (atomicAdd) + weight prep, one dispatch ----------------
// blocks 0..2047: per-batch partial sum/sumsq -> atomicAdd st[b*2..]. st must be
// zeroed (hipMemsetAsync) before launch.
// blocks 2048..2623: qkv_w transpose tiles; 2624..2815: lin_w cast.
__global__ __launch_bounds__(256) void k_r1p(const float* __restrict__ x,
                                             float* __restrict__ st,
                                             const float* __restrict__ qw,
                                             u16* __restrict__ qwT,
                                             const float* __restrict__ lw,
                                             u16* __restrict__ lwB) {
  const int bid = blockIdx.x, tid = threadIdx.x;
  if (bid < 2048) {
    const int b = bid >> 7, blk = bid & 127;
    const float4* xb = (const float4*)(x + (size_t)b * PE + (size_t)blk * 12288);
    float s = 0.f, q = 0.f;
#pragma unroll
    for (int i = 0; i < 12; ++i) {
      float4 v = xb[tid + i * 256];
      s += v.x + v.y + v.z + v.w;
      q += v.x * v.x + v.y * v.y + v.z * v.z + v.w * v.w;
    }
    for (int off = 32; off > 0; off >>= 1) { s += __shfl_down(s, off); q += __shfl_down(q, off); }
    __shared__ float ls[4], lq[4];
    if ((tid & 63) == 0) { ls[tid >> 6] = s; lq[tid >> 6] = q; }
    __syncthreads();
    if (tid == 0) {
      atomicAdd(&st[b * 2],     ls[0] + ls[1] + ls[2] + ls[3]);
      atomicAdd(&st[b * 2 + 1], lq[0] + lq[1] + lq[2] + lq[3]);
    }
  } else if (bid < 2624) {
    // qkv_w [E][3H] fp32 -> qwT [n][e] bf16
    __shared__ float tsh[32][33];
    const int pb = bid - 2048;
    const int e0 = (pb % 24) * 32, n0 = (pb / 24) * 32;
    const int tx = tid & 31, ty = tid >> 5;  // 32x8
#pragma unroll
    for (int j = 0; j < 4; ++j)
      tsh[ty + j * 8][tx] = qw[(size_t)(e0 + ty + j * 8) * 768 + n0 + tx];
    __syncthreads();
#pragma unroll
    for (int j = 0; j < 4; ++j)
      qwT[(size_t)(n0 + ty + j * 8) * 768 + e0 + tx] = f2bf(tsh[tx][ty + j * 8]);
  } else {
    const int i = (bid - 2624) * 256 + tid;
    if (i < 768 * 256 / 4) {
      float4 v = ((const float4*)lw)[i];
      ushort4 o;
      o.x = f2bf(v.x); o.y = f2bf(v.y); o.z = f2bf(v.z); o.w = f2bf(v.w);
      ((ushort4*)lwB)[i] = o;
    }
  }
}

__global__ __launch_bounds__(256) void k_ln(const float* __restrict__ x,
                                            const float* __restrict__ w,
                                            const float* __restrict__ bia,
                                            const float* __restrict__ st,
                                            u16* __restrict__ xn) {
  const float4* x4 = (const float4*)x;
  const float4* w4 = (const float4*)w;
  const float4* b4 = (const float4*)bia;
  const float invN = 1.f / (float)PE;
  for (int vi = blockIdx.x * 256 + threadIdx.x; vi < (PE / 4) * BB; vi += gridDim.x * 256) {
    int bidx = vi / (PE / 4);
    int wi = vi - bidx * (PE / 4);
    float4 xv = x4[vi], wv = w4[wi], bv = b4[wi];
    float mean = st[bidx * 2] * invN;
    float rstd = rsqrtf(st[bidx * 2 + 1] * invN - mean * mean + 1e-5f);
    ushort4 o;
    o.x = f2bf((xv.x - mean) * rstd * wv.x + bv.x);
    o.y = f2bf((xv.y - mean) * rstd * wv.y + bv.y);
    o.z = f2bf((xv.z - mean) * rstd * wv.z + bv.z);
    o.w = f2bf((xv.w - mean) * rstd * wv.w + bv.w);
    ((ushort4*)xn)[vi] = o;
  }
}

// ---------------- QKV GEMM with fused K/V transpose (round-4 proven) ----------------
__global__ __launch_bounds__(256) void k_gemm_qkv(const u16* __restrict__ xn,
                                                  const u16* __restrict__ wT,
                                                  u16* __restrict__ q_buf,
                                                  u16* __restrict__ kT,
                                                  u16* __restrict__ vT) {
  __shared__ __align__(16) u16 sbuf[128 * 64 * 2];
  u16* As = sbuf;
  u16* Bs = sbuf + 128 * 64;
  floatx4 acc[4][4];
  zero_acc4(acc);
  const int t = xcd_remap(blockIdx.x, 1536);
  const int xt = t % 6, yt = t / 6;          // yt in [0,256): b = yt>>4, ptile = yt&15
  const int tM = yt * 128, tN = xt * 128;
  gemm_core(xn + (size_t)tM * EE, EE, wT + (size_t)tN * EE, EE, 12, As, Bs, acc);

  if (xt < 2) {
    epilogue4(acc, [&](int gr, int gc, float v) {
      q_buf[(size_t)(tM + gr) * HH + xt * 128 + gc] = f2bf(v);
    });
  } else {
    const int b = yt >> 4;
    const int p_base = (yt & 15) * 128;
    u16* dst = ((xt < 4) ? kT : vT) + (size_t)b * (HH * PP);
    const int dbase = (xt - ((xt < 4) ? 2 : 4)) * 128;
    u16 (*tp)[144] = (u16(*)[144])sbuf;      // 64 x 144 (18432 B)
    const int tid = threadIdx.x;
    const int lane = tid & 63;
    const int wr = (tid >> 7) & 1, wc = (tid >> 6) & 1;
    const int r0 = (lane >> 4) * 4, c0 = lane & 15;
#pragma unroll
    for (int h = 0; h < 2; ++h) {
      __syncthreads();
      if (wc == h) {
#pragma unroll
        for (int i = 0; i < 4; ++i)
#pragma unroll
          for (int j = 0; j < 4; ++j)
#pragma unroll
            for (int r = 0; r < 4; ++r)
              tp[j * 16 + c0][wr * 64 + i * 16 + r0 + r] = f2bf(acc[i][j][r]);
      }
      __syncthreads();
#pragma unroll
      for (int pass = 0; pass < 4; ++pass) {
        const int row = pass * 16 + (tid >> 4);
        const int p8 = (tid & 15) * 8;
        const int d = dbase + h * 64 + row;
        uint4 vdat = *(const uint4*)&tp[row][p8];
        *(uint4*)&dst[(size_t)d * PP + p_base + p8] = vdat;
      }
    }
  }
}

// ---------------- tail GEMMs: 64x64 single-wave ----------------
// G partials: part[z][d1][d2] = sum_{p in slice s} kT[d1][p] vT[d2][p], z=b*8+s
__global__ __launch_bounds__(64) void k_w2_64(const u16* __restrict__ kT,
                                              const u16* __restrict__ vT,
                                              float* __restrict__ part) {
  __shared__ __align__(16) u16 sbuf[64 * 64 * 2];
  floatx4 acc[4][4];
  zero_acc4(acc);
  const int t = xcd_remap(blockIdx.x, 2048);
  const int xt = t & 3, yt = (t >> 2) & 3, z = t >> 4;   // z = b*8+s
  const int b = z >> 3, s = z & 7;
  const int tM = yt * 64, tN = xt * 64;
  const u16* A = kT + (size_t)b * (HH * PP) + (size_t)tM * PP + s * 256;
  const u16* B = vT + (size_t)b * (HH * PP) + (size_t)tN * PP + s * 256;
  gemm64_core(A, PP, B, PP, 4, sbuf, sbuf + 64 * 64, acc);
  float* P = part + (size_t)z * 65536;
  epilogue64(acc, [&](int gr, int gc, float v) {
    P[(size_t)(tM + gr) * 256 + tN + gc] = v;
  });
}

__global__ void k_reduce_w2(const float* __restrict__ part, u16* __restrict__ W2) {
  const int idx = blockIdx.x * 256 + threadIdx.x;
  const int b = idx >> 16, i = idx & 65535;
  const float* p = part + ((size_t)b << 19) + i;
  float s = 0.f;
#pragma unroll
  for (int t = 0; t < 8; ++t) s += p[(size_t)t << 16];
  W2[idx] = f2bf(s);
}

// M2T[e][d1] = sum_d2 lw[e][d2] * G[d1][d2]
__global__ __launch_bounds__(64) void k_m2_64(const u16* __restrict__ lwB,
                                              const u16* __restrict__ W2,
                                              u16* __restrict__ M2T) {
  __shared__ __align__(16) u16 sbuf[64 * 64 * 2];
  floatx4 acc[4][4];
  zero_acc4(acc);
  const int t = xcd_remap(blockIdx.x, 768);
  const int xt = t & 3, yt = (t >> 2) % 12, b = t / 48;
  const int tM = yt * 64, tN = xt * 64;
  const u16* A = lwB + (size_t)tM * HH;
  const u16* B = W2 + (size_t)b * 65536 + (size_t)tN * HH;
  gemm64_core(A, HH, B, HH, 4, sbuf, sbuf + 64 * 64, acc);
  u16* Mb = M2T + (size_t)b * (EE * HH);
  epilogue64(acc, [&](int gr, int gc, float v) {
    Mb[(size_t)(tM + gr) * HH + tN + gc] = f2bf(v);
  });
}

// out[p][e] = relu(sum_d1 q[p][d1] * M2T[e][d1] + lb[e])
__global__ __launch_bounds__(64) void k_out_64(const u16* __restrict__ q_buf,
                                               const u16* __restrict__ M2T,
                                               const float* __restrict__ lb,
                                               float* __restrict__ out) {
  __shared__ __align__(16) u16 sbuf[64 * 64 * 2];
  floatx4 acc[4][4];
  zero_acc4(acc);
  const int t = xcd_remap(blockIdx.x, 6144);
  const int xt = t % 12, yt = (t / 12) % 32, b = t / 384;
  const int tM = yt * 64, tN = xt * 64;
  const u16* A = q_buf + (size_t)b * (PP * HH) + (size_t)tM * HH;
  const u16* B = M2T + (size_t)b * (EE * HH) + (size_t)tN * HH;
  gemm64_core(A, HH, B, HH, 4, sbuf, sbuf + 64 * 64, acc);
  float* ob = out + (size_t)b * PE;
  epilogue64(acc, [&](int gr, int gc, float v) {
    ob[(size_t)(tM + gr) * EE + tN + gc] = fmaxf(v + lb[tN + gc], 0.f);
  });
}

// ---------------- launch ----------------
extern "C" void kernel_launch(void* const* d_in, const int* in_sizes, int n_in,
                              void* d_out, int out_size, void* d_ws, size_t ws_size,
                              hipStream_t stream) {
  (void)in_sizes; (void)n_in; (void)out_size;
  const float* x  = (const float*)d_in[0];
  const float* nw = (const float*)d_in[1];
  const float* nb = (const float*)d_in[2];
  const float* qw = (const float*)d_in[3];
  const float* lw = (const float*)d_in[4];
  const float* lb = (const float*)d_in[5];
  float* out = (float*)d_out;
  char* ws = (char*)d_ws;

  size_t off = 0;
  auto alloc = [&](size_t bytes) { size_t o = off; off += (bytes + 255) & ~(size_t)255; return o; };
  const size_t o_st   = alloc(16 * 2 * 4);
  const size_t o_qwT  = alloc((size_t)768 * 768 * 2);
  const size_t o_lwB  = alloc((size_t)768 * 256 * 2);
  const size_t o_q    = alloc((size_t)MM * HH * 2);        // 16.8 MB
  const size_t o_kT   = alloc((size_t)BB * HH * PP * 2);   // 16.8 MB
  const size_t o_vT   = alloc((size_t)BB * HH * PP * 2);   // 16.8 MB
  const size_t o_W2   = alloc((size_t)BB * HH * HH * 2);   // 2.1 MB
  const size_t o_M2T  = alloc((size_t)BB * EE * HH * 2);   // 6.3 MB
  const size_t need_base = off;
  const size_t region = (size_t)MM * EE * 2;  // xn (50.3MB) >= part (33.6MB)

  // xn and part have disjoint lifetimes -> share one region; spill to d_out
  // (100.7MB fp32, dead until k_out_64) if ws is too small.
  char* big = (ws_size >= need_base + region) ? (ws + need_base) : (char*)d_out;

  float* st   = (float*)(ws + o_st);
  u16* qwT    = (u16*)(ws + o_qwT);
  u16* lwB    = (u16*)(ws + o_lwB);
  u16* q_buf  = (u16*)(ws + o_q);
  u16* kT     = (u16*)(ws + o_kT);
  u16* vT     = (u16*)(ws + o_vT);
  u16* W2     = (u16*)(ws + o_W2);
  u16* M2T    = (u16*)(ws + o_M2T);
  u16* xn     = (u16*)big;
  float* part = (float*)big;

  hipMemsetAsync(st, 0, 16 * 2 * 4, stream);
  k_r1p<<<2816, 256, 0, stream>>>(x, st, qw, qwT, lw, lwB);
  k_ln<<<2048, 256, 0, stream>>>(x, nw, nb, st, xn);
  k_gemm_qkv<<<1536, 256, 0, stream>>>(xn, qwT, q_buf, kT, vT);
  k_w2_64<<<2048, 64, 0, stream>>>(kT, vT, part);
  k_reduce_w2<<<4096, 256, 0, stream>>>(part, W2);
  k_m2_64<<<768, 64, 0, stream>>>(lwB, W2, M2T);
  k_out_64<<<6144, 64, 0, stream>>>(q_buf, M2T, lb, out);
}